// Round 6
// baseline (728.208 us; speedup 1.0000x reference)
//
#include <hip/hip_runtime.h>
#include <cstddef>

#define B_SZ 64
#define HID_ 4096
#define NH_ 32
#define NKV_ 8
#define HD_ 128
#define T_ 4096
#define QKV_COLS 6144                  // (NH + 2*NKV) * HD
#define SCALE_ 0.08838834764831845f    // 128^-0.5

#define KS1 8                          // split-K for QKV gemm (192 blocks)
#define KCH1 (HID_ / KS1)              // 512 k-steps
#define KS2 16                         // split-K for O gemm (256 blocks)
#define KCH2 (HID_ / KS2)              // 256 k-steps

#define SPLIT_ 8
#define KPB 512                        // keys per (b,sp) block
#define NIT 64                         // KPB/8 keys-per-wave-iter
#define SROW 520                       // score-row stride in LDS floats

typedef float f4 __attribute__((ext_vector_type(4)));

#define FMA4(A, S, V) { A.x = fmaf(S, V.x, A.x); A.y = fmaf(S, V.y, A.y); \
                        A.z = fmaf(S, V.z, A.z); A.w = fmaf(S, V.w, A.w); }

// ---------------------------------------------------------------- X transpose
__global__ __launch_bounds__(256) void transpose_k(const float* __restrict__ X,
                                                   float* __restrict__ XT) {
  const int idx = blockIdx.x * 256 + threadIdx.x;
  const int k = idx >> 6, r = idx & 63;
  XT[idx] = X[(size_t)r * HID_ + k];
}

// ---------------------------------------------------------------- GEMM
// part[z][64][ncol] = X[64][4096] @ W[4096][ncol]; block = 256 cols x all 64
// rows x kch k-steps. W coalesced (1 load feeds 64 FMAs); X block-uniform
// scalar loads from XT. W prefetch depth 16 -> ~16KB/CU in flight.
__global__ __launch_bounds__(256) void gemm_k(const float* __restrict__ XT,
                                              const float* __restrict__ W,
                                              float* __restrict__ part,
                                              int ncol, int kch) {
  const int tid = threadIdx.x;
  const int col = blockIdx.x * 256 + tid;
  const int k0 = blockIdx.z * kch;

  float acc[64];
#pragma unroll
  for (int r = 0; r < 64; ++r) acc[r] = 0.f;

  const float* wp = W + (size_t)k0 * ncol + col;
  const float* xp = XT + (size_t)k0 * 64;

  float w[16];
#pragma unroll
  for (int u = 0; u < 16; ++u) w[u] = wp[(size_t)u * ncol];

  for (int k = 0; k < kch; k += 16) {
    float n[16] = {0.f, 0.f, 0.f, 0.f, 0.f, 0.f, 0.f, 0.f,
                   0.f, 0.f, 0.f, 0.f, 0.f, 0.f, 0.f, 0.f};
    if (k + 16 < kch) {
      const float* wq = wp + (size_t)(k + 16) * ncol;
#pragma unroll
      for (int u = 0; u < 16; ++u) n[u] = wq[(size_t)u * ncol];
    }
#pragma unroll
    for (int u = 0; u < 16; ++u) {
      const float* xk = xp + (size_t)(k + u) * 64;   // block-uniform -> s_load
#pragma unroll
      for (int r = 0; r < 64; ++r) acc[r] = fmaf(xk[r], w[u], acc[r]);
    }
#pragma unroll
    for (int u = 0; u < 16; ++u) w[u] = n[u];
  }

  float* pp = part + (size_t)blockIdx.z * 64 * ncol + col;
#pragma unroll
  for (int r = 0; r < 64; ++r) pp[(size_t)r * ncol] = acc[r];
}

__global__ __launch_bounds__(256) void reduce_k(const float* __restrict__ part,
                                                float* __restrict__ out, int n, int ks) {
  const int i4 = (blockIdx.x * 256 + threadIdx.x) * 4;
  if (i4 >= n) return;
  float4 s = *(const float4*)(part + i4);
  for (int k = 1; k < ks; ++k) {
    float4 t = *(const float4*)(part + (size_t)k * n + i4);
    s.x += t.x; s.y += t.y; s.z += t.z; s.w += t.w;
  }
  *(float4*)(out + i4) = s;
}

// ---------------------------------------------------------------- fused reduce(KS1 partials) + RoPE
// grid (b, 48): hh 0..31 q heads -> qr, 32..39 k heads -> kn, 40..47 v -> vn
__global__ __launch_bounds__(64) void reduce_rope_k(const float* __restrict__ part,
                                                    const int* __restrict__ pos,
                                                    float* __restrict__ qr,
                                                    float* __restrict__ kn,
                                                    float* __restrict__ vn) {
  const int b = blockIdx.x;
  const int hh = blockIdx.y;
  const int d = threadIdx.x;            // 0..63 (pair index)
  const size_t base = (size_t)b * QKV_COLS + hh * HD_ + d;
  float s0 = 0.f, s1 = 0.f;
#pragma unroll
  for (int k = 0; k < KS1; ++k) {
    const float* pk = part + (size_t)k * 64 * QKV_COLS + base;
    s0 += pk[0];
    s1 += pk[64];
  }
  if (hh < 40) {
    const float p = (float)pos[b];
    const float invf = (float)pow(10000.0, -(double)d / 64.0);
    float sn, cs;
    sincosf(p * invf, &sn, &cs);
    const float o0 = s0 * cs - s1 * sn;
    const float o1 = s1 * cs + s0 * sn;
    if (hh < 32) {
      float* dst = qr + ((size_t)b * NH_ + hh) * HD_;
      dst[d] = o0;
      dst[d + 64] = o1;
    } else {
      float* dst = kn + ((size_t)b * NKV_ + (hh - 32)) * HD_;
      dst[d] = o0;
      dst[d + 64] = o1;
    }
  } else {
    float* dst = vn + ((size_t)b * NKV_ + (hh - 40)) * HD_;
    dst[d] = s0;
    dst[d + 64] = s1;
  }
}

// ---------------------------------------------------------------- attention
__device__ __forceinline__ void load_row4_nt(const float* p, f4 r[4]) {
  r[0] = __builtin_nontemporal_load((const f4*)(p));
  r[1] = __builtin_nontemporal_load((const f4*)(p + 32));
  r[2] = __builtin_nontemporal_load((const f4*)(p + 64));
  r[3] = __builtin_nontemporal_load((const f4*)(p + 96));
}
__device__ __forceinline__ void load_row4(const float* p, f4 r[4]) {
  r[0] = *(const f4*)(p);
  r[1] = *(const f4*)(p + 32);
  r[2] = *(const f4*)(p + 64);
  r[3] = *(const f4*)(p + 96);
}

// Block = (b, split): 8 waves, wave w = kv-head g=w. The 8 waves together
// consume every byte of each 4KB key row -> sequential HBM streaming.
// 8 lanes/key (cg), 8 key-owners/wave (ko). Q + PV acc in registers;
// cross-ko reduce via shfl butterfly (no LDS).
__global__ __launch_bounds__(512, 2) void attn4_k(const float* __restrict__ kc,
                                                  const float* __restrict__ vc,
                                                  const float* __restrict__ qr,
                                                  const float* __restrict__ kn,
                                                  const float* __restrict__ vn,
                                                  float* __restrict__ part) {
  __shared__ float sc[NKV_][4][SROW];               // scores / probs

  const int b = blockIdx.x, sp = blockIdx.y;
  const int tid = threadIdx.x;
  const int w = tid >> 6, l = tid & 63;             // wave = kv head g
  const int cg = l & 7, ko = l >> 3;
  const bool has_new = (sp == SPLIT_ - 1);

  // Q fragments: q4[h][i] covers cols i*32 + cg*4 .. +3 of head w*4+h
  f4 q4[4][4];
  const float* qb = qr + (size_t)(b * NH_ + w * 4) * HD_ + cg * 4;
#pragma unroll
  for (int h = 0; h < 4; ++h)
#pragma unroll
    for (int i = 0; i < 4; ++i) {
      f4 t = *(const f4*)(qb + h * HD_ + i * 32);
      q4[h][i] = t * SCALE_;
    }

  const size_t row_stride = (size_t)NKV_ * HD_;
  const float* kb = kc + ((size_t)(b * T_ + sp * KPB) * NKV_ + w) * HD_ + cg * 4;
  const float* vb = vc + ((size_t)(b * T_ + sp * KPB) * NKV_ + w) * HD_ + cg * 4;

  // ---- phase 1: scores (NIT iters x 8 keys/wave)
  {
    f4 kx[4];
    load_row4_nt(kb + (size_t)ko * row_stride, kx);
    for (int it = 0; it < NIT; ++it) {
      f4 nx[4];
      const int itn = (it + 1) & (NIT - 1);
      load_row4_nt(kb + (size_t)(itn * 8 + ko) * row_stride, nx);
      float s[4] = {0.f, 0.f, 0.f, 0.f};
#pragma unroll
      for (int i = 0; i < 4; ++i) {
#pragma unroll
        for (int h = 0; h < 4; ++h) {
          s[h] = fmaf(q4[h][i].x, kx[i].x, s[h]);
          s[h] = fmaf(q4[h][i].y, kx[i].y, s[h]);
          s[h] = fmaf(q4[h][i].z, kx[i].z, s[h]);
          s[h] = fmaf(q4[h][i].w, kx[i].w, s[h]);
        }
      }
#pragma unroll
      for (int h = 0; h < 4; ++h) {
        s[h] += __shfl_xor(s[h], 1);
        s[h] += __shfl_xor(s[h], 2);
        s[h] += __shfl_xor(s[h], 4);
      }
      if (cg == 0) {
        const int key = it * 8 + ko;
#pragma unroll
        for (int h = 0; h < 4; ++h) sc[w][h][key] = s[h];
      }
#pragma unroll
      for (int i = 0; i < 4; ++i) kx[i] = nx[i];
    }
  }

  // ---- new-token scores for the wave's 4 heads
  if (has_new) {
    const float* kp = kn + (size_t)(b * NKV_ + w) * HD_ + cg * 4;
    f4 kx2[4];
    load_row4(kp, kx2);
    float s[4] = {0.f, 0.f, 0.f, 0.f};
#pragma unroll
    for (int i = 0; i < 4; ++i) {
#pragma unroll
      for (int h = 0; h < 4; ++h) {
        s[h] = fmaf(q4[h][i].x, kx2[i].x, s[h]);
        s[h] = fmaf(q4[h][i].y, kx2[i].y, s[h]);
        s[h] = fmaf(q4[h][i].z, kx2[i].z, s[h]);
        s[h] = fmaf(q4[h][i].w, kx2[i].w, s[h]);
      }
    }
#pragma unroll
    for (int h = 0; h < 4; ++h) {
      s[h] += __shfl_xor(s[h], 1);
      s[h] += __shfl_xor(s[h], 2);
      s[h] += __shfl_xor(s[h], 4);
    }
    if (l == 0) {
#pragma unroll
      for (int h = 0; h < 4; ++h) sc[w][h][KPB] = s[h];
    }
  }

  // ---- early V issue: first V rows fly during softmax
  f4 vx[4];
  load_row4_nt(vb + (size_t)ko * row_stride, vx);

  __syncthreads();

  // ---- softmax: wave w does its 4 heads over KPB keys
#pragma unroll
  for (int h = 0; h < 4; ++h) {
    float vals[KPB / 64];
    float mloc = -1e30f;
#pragma unroll
    for (int j = 0; j < KPB / 64; ++j) {
      vals[j] = sc[w][h][j * 64 + l];
      mloc = fmaxf(mloc, vals[j]);
    }
#pragma unroll
    for (int m = 32; m > 0; m >>= 1) mloc = fmaxf(mloc, __shfl_xor(mloc, m));
    float s_extra = 0.f;
    if (has_new) {
      s_extra = sc[w][h][KPB];
      mloc = fmaxf(mloc, s_extra);
    }
    float lsum = 0.f;
#pragma unroll
    for (int j = 0; j < KPB / 64; ++j) {
      float e = expf(vals[j] - mloc);
      lsum += e;
      sc[w][h][j * 64 + l] = e;
    }
#pragma unroll
    for (int m = 32; m > 0; m >>= 1) lsum += __shfl_xor(lsum, m);
    if (has_new) {
      float en = expf(s_extra - mloc);
      lsum += en;
      if (l == 0) sc[w][h][KPB] = en;
    }
    if (l == 0) {
      float* pp = part + ((size_t)(b * NH_ + w * 4 + h) * SPLIT_ + sp) * 130;
      pp[128] = mloc;
      pp[129] = lsum;
    }
  }
  __syncthreads();

  // ---- phase 2: PV
  f4 acc[4][4];
#pragma unroll
  for (int h = 0; h < 4; ++h)
#pragma unroll
    for (int i = 0; i < 4; ++i) acc[h][i] = (f4){0.f, 0.f, 0.f, 0.f};

  for (int it = 0; it < NIT; ++it) {
    f4 nx[4];
    const int itn = (it + 1) & (NIT - 1);
    load_row4_nt(vb + (size_t)(itn * 8 + ko) * row_stride, nx);
    const int key = it * 8 + ko;
    float p[4];
#pragma unroll
    for (int h = 0; h < 4; ++h) p[h] = sc[w][h][key];
#pragma unroll
    for (int h = 0; h < 4; ++h)
#pragma unroll
      for (int i = 0; i < 4; ++i) FMA4(acc[h][i], p[h], vx[i]);
#pragma unroll
    for (int i = 0; i < 4; ++i) vx[i] = nx[i];
  }

  if (has_new && ko == 0) {   // lanes cg=0..7 cover all 128 cols once
    const float* vp = vn + (size_t)(b * NKV_ + w) * HD_ + cg * 4;
    f4 vx2[4];
    load_row4(vp, vx2);
#pragma unroll
    for (int h = 0; h < 4; ++h) {
      const float en = sc[w][h][KPB];
#pragma unroll
      for (int i = 0; i < 4; ++i) FMA4(acc[h][i], en, vx2[i]);
    }
  }

  // ---- in-wave butterfly reduce across the 8 key-owners
#pragma unroll
  for (int mask = 8; mask <= 32; mask <<= 1) {
#pragma unroll
    for (int h = 0; h < 4; ++h)
#pragma unroll
      for (int i = 0; i < 4; ++i) {
        acc[h][i].x += __shfl_xor(acc[h][i].x, mask);
        acc[h][i].y += __shfl_xor(acc[h][i].y, mask);
        acc[h][i].z += __shfl_xor(acc[h][i].z, mask);
        acc[h][i].w += __shfl_xor(acc[h][i].w, mask);
      }
  }
  if (ko == 0) {
#pragma unroll
    for (int h = 0; h < 4; ++h) {
      float* pp = part + ((size_t)(b * NH_ + w * 4 + h) * SPLIT_ + sp) * 130 + cg * 4;
#pragma unroll
      for (int i = 0; i < 4; ++i) *(f4*)(pp + i * 32) = acc[h][i];
    }
  }
}

// ---------------------------------------------------------------- merge splits
// writes ctx TRANSPOSED: ctxt[col(4096)][b(64)] so gemm2 can scalar-load it
__global__ __launch_bounds__(64) void merge_k(const float* __restrict__ part,
                                              float* __restrict__ ctxt) {
  const int bh = blockIdx.x;
  const int b = bh >> 5, h = bh & 31;
  const int l = threadIdx.x;
  const float* pbase = part + (size_t)bh * SPLIT_ * 130;
  float m_g = -1e30f;
#pragma unroll
  for (int sp = 0; sp < SPLIT_; ++sp) m_g = fmaxf(m_g, pbase[sp * 130 + 128]);
  float scale[SPLIT_];
  float l_g = 0.f;
#pragma unroll
  for (int sp = 0; sp < SPLIT_; ++sp) {
    scale[sp] = expf(pbase[sp * 130 + 128] - m_g);
    l_g += scale[sp] * pbase[sp * 130 + 129];
  }
  const float inv = 1.f / l_g;
  float c0 = 0.f, c1 = 0.f;
#pragma unroll
  for (int sp = 0; sp < SPLIT_; ++sp) {
    c0 += scale[sp] * pbase[sp * 130 + 2 * l];
    c1 += scale[sp] * pbase[sp * 130 + 2 * l + 1];
  }
  ctxt[((size_t)(h * HD_ + 2 * l)) * 64 + b] = c0 * inv;
  ctxt[((size_t)(h * HD_ + 2 * l + 1)) * 64 + b] = c1 * inv;
}

extern "C" void kernel_launch(void* const* d_in, const int* in_sizes, int n_in,
                              void* d_out, int out_size, void* d_ws, size_t ws_size,
                              hipStream_t stream) {
  const int* positions = (const int*)d_in[0];
  const float* hidden = (const float*)d_in[1];
  const float* k_cache = (const float*)d_in[2];
  const float* v_cache = (const float*)d_in[3];
  const float* w_qkv = (const float*)d_in[4];
  const float* w_o = (const float*)d_in[5];
  float* out = (float*)d_out;

  float* ws = (float*)d_ws;
  float* partA = ws;                                    // max(8*64*6144, 16*64*4096) = 4194304
  float* qr = partA + (size_t)16 * 64 * HID_;           // 262144
  float* kn = qr + (size_t)64 * NH_ * HD_;              // 65536
  float* vn = kn + (size_t)64 * NKV_ * HD_;             // 65536
  float* apart = vn + (size_t)64 * NKV_ * HD_;          // 64*32*8*130 = 2129920
  float* xt = apart + (size_t)64 * NH_ * SPLIT_ * 130;  // 262144
  float* ctxt = xt + (size_t)64 * HID_;                 // 262144

  transpose_k<<<1024, 256, 0, stream>>>(hidden, xt);
  gemm_k<<<dim3(QKV_COLS / 256, 1, KS1), 256, 0, stream>>>(xt, w_qkv, partA, QKV_COLS, KCH1);
  reduce_rope_k<<<dim3(B_SZ, 48), 64, 0, stream>>>(partA, positions, qr, kn, vn);
  attn4_k<<<dim3(B_SZ, SPLIT_), 512, 0, stream>>>(k_cache, v_cache, qr, kn, vn, apart);
  merge_k<<<B_SZ * NH_, 64, 0, stream>>>(apart, ctxt);
  gemm_k<<<dim3(HID_ / 256, 1, KS2), 256, 0, stream>>>(ctxt, w_o, partA, HID_, KCH2);
  reduce_k<<<(64 * HID_) / 1024, 256, 0, stream>>>(partA, out, 64 * HID_, KS2);
}

// Round 7
// 494.626 us; speedup vs baseline: 1.4722x; 1.4722x over previous
//
#include <hip/hip_runtime.h>
#include <cstddef>

#define B_SZ 64
#define HID_ 4096
#define NH_ 32
#define NKV_ 8
#define HD_ 128
#define T_ 4096
#define QKV_COLS 6144                  // (NH + 2*NKV) * HD
#define SCALE_ 0.08838834764831845f    // 128^-0.5

#define KS 32                          // split-K for both GEMMs (768/512 blocks: keep >=2 blocks/CU!)
#define G_KCH (HID_ / KS)              // 128 k-steps per block

#define SPLIT_ 8
#define KPB 512                        // keys per (b,sp) block
#define NIT 64                         // KPB/8 keys-per-wave-iter
#define SROW 520                       // score-row stride in LDS floats

typedef float f4 __attribute__((ext_vector_type(4)));

#define FMA4(A, S, V) { A.x = fmaf(S, V.x, A.x); A.y = fmaf(S, V.y, A.y); \
                        A.z = fmaf(S, V.z, A.z); A.w = fmaf(S, V.w, A.w); }

// ---------------------------------------------------------------- X transpose
__global__ __launch_bounds__(256) void transpose_k(const float* __restrict__ X,
                                                   float* __restrict__ XT) {
  const int idx = blockIdx.x * 256 + threadIdx.x;
  const int k = idx >> 6, r = idx & 63;
  XT[idx] = X[(size_t)r * HID_ + k];
}

// ---------------------------------------------------------------- GEMM (R5 structure)
// part[z][64][ncol] = X[64][4096] @ W[4096][ncol]; one block = 256 cols x
// ALL 64 rows x 128 k-steps. W coalesced nt-loads (read once grid-wide,
// 1 load feeds 64 FMAs); X block-uniform scalar loads from XT. Depth-4
// named-scalar prefetch. 768/512 blocks -> 12/8 waves per CU (TLP).
__global__ __launch_bounds__(256) void gemm_k(const float* __restrict__ XT,
                                              const float* __restrict__ W,
                                              float* __restrict__ part, int ncol) {
  const int tid = threadIdx.x;
  const int col = blockIdx.x * 256 + tid;
  const int k0 = blockIdx.z * G_KCH;

  float acc[64];
#pragma unroll
  for (int r = 0; r < 64; ++r) acc[r] = 0.f;

  const float* wp = W + (size_t)k0 * ncol + col;
  const float* xp = XT + (size_t)k0 * 64;

  float w0 = __builtin_nontemporal_load(wp);
  float w1 = __builtin_nontemporal_load(wp + (size_t)1 * ncol);
  float w2 = __builtin_nontemporal_load(wp + (size_t)2 * ncol);
  float w3 = __builtin_nontemporal_load(wp + (size_t)3 * ncol);

  for (int k = 0; k < G_KCH; k += 4) {
    float n0 = 0.f, n1 = 0.f, n2 = 0.f, n3 = 0.f;
    if (k + 4 < G_KCH) {
      const float* wq = wp + (size_t)(k + 4) * ncol;
      n0 = __builtin_nontemporal_load(wq);
      n1 = __builtin_nontemporal_load(wq + (size_t)1 * ncol);
      n2 = __builtin_nontemporal_load(wq + (size_t)2 * ncol);
      n3 = __builtin_nontemporal_load(wq + (size_t)3 * ncol);
    }
#pragma unroll
    for (int u = 0; u < 4; ++u) {
      const float wv = (u == 0) ? w0 : (u == 1) ? w1 : (u == 2) ? w2 : w3;
      const float* xk = xp + (size_t)(k + u) * 64;   // block-uniform -> s_load
#pragma unroll
      for (int r = 0; r < 64; ++r) acc[r] = fmaf(xk[r], wv, acc[r]);
    }
    w0 = n0; w1 = n1; w2 = n2; w3 = n3;
  }

  float* pp = part + (size_t)blockIdx.z * 64 * ncol + col;
#pragma unroll
  for (int r = 0; r < 64; ++r) pp[(size_t)r * ncol] = acc[r];
}

__global__ __launch_bounds__(256) void reduce_k(const float* __restrict__ part,
                                                float* __restrict__ out, int n) {
  const int i4 = (blockIdx.x * 256 + threadIdx.x) * 4;
  if (i4 >= n) return;
  f4 s = __builtin_nontemporal_load((const f4*)(part + i4));
#pragma unroll
  for (int k = 1; k < KS; ++k) {
    f4 t = __builtin_nontemporal_load((const f4*)(part + (size_t)k * n + i4));
    s += t;
  }
  __builtin_nontemporal_store(s, (f4*)(out + i4));
}

// ---------------------------------------------------------------- fused reduce(KS partials) + RoPE
// grid (b, 48): hh 0..31 q heads -> qr, 32..39 k heads -> kn, 40..47 v -> vn
__global__ __launch_bounds__(64) void reduce_rope_k(const float* __restrict__ part,
                                                    const int* __restrict__ pos,
                                                    float* __restrict__ qr,
                                                    float* __restrict__ kn,
                                                    float* __restrict__ vn) {
  const int b = blockIdx.x;
  const int hh = blockIdx.y;
  const int d = threadIdx.x;            // 0..63 (pair index)
  const size_t base = (size_t)b * QKV_COLS + hh * HD_ + d;
  float s0 = 0.f, s1 = 0.f;
#pragma unroll
  for (int k = 0; k < KS; ++k) {
    const float* pk = part + (size_t)k * 64 * QKV_COLS + base;
    s0 += __builtin_nontemporal_load(pk);
    s1 += __builtin_nontemporal_load(pk + 64);
  }
  if (hh < 40) {
    const float p = (float)pos[b];
    const float invf = (float)pow(10000.0, -(double)d / 64.0);
    float sn, cs;
    sincosf(p * invf, &sn, &cs);
    const float o0 = s0 * cs - s1 * sn;
    const float o1 = s1 * cs + s0 * sn;
    if (hh < 32) {
      float* dst = qr + ((size_t)b * NH_ + hh) * HD_;
      dst[d] = o0;
      dst[d + 64] = o1;
    } else {
      float* dst = kn + ((size_t)b * NKV_ + (hh - 32)) * HD_;
      dst[d] = o0;
      dst[d + 64] = o1;
    }
  } else {
    float* dst = vn + ((size_t)b * NKV_ + (hh - 40)) * HD_;
    dst[d] = s0;
    dst[d + 64] = s1;
  }
}

// ---------------------------------------------------------------- attention
__device__ __forceinline__ void load_row4_nt(const float* p, f4 r[4]) {
  r[0] = __builtin_nontemporal_load((const f4*)(p));
  r[1] = __builtin_nontemporal_load((const f4*)(p + 32));
  r[2] = __builtin_nontemporal_load((const f4*)(p + 64));
  r[3] = __builtin_nontemporal_load((const f4*)(p + 96));
}
__device__ __forceinline__ void load_row4(const float* p, f4 r[4]) {
  r[0] = *(const f4*)(p);
  r[1] = *(const f4*)(p + 32);
  r[2] = *(const f4*)(p + 64);
  r[3] = *(const f4*)(p + 96);
}

// Block = (b, split): 8 waves, wave w = kv-head g=w. The 8 waves together
// consume every byte of each 4KB key row -> sequential HBM streaming.
// 8 lanes/key (cg), 8 key-owners/wave (ko). Q + PV acc in registers;
// cross-ko reduce via shfl butterfly (no LDS).
__global__ __launch_bounds__(512, 2) void attn4_k(const float* __restrict__ kc,
                                                  const float* __restrict__ vc,
                                                  const float* __restrict__ qr,
                                                  const float* __restrict__ kn,
                                                  const float* __restrict__ vn,
                                                  float* __restrict__ part) {
  __shared__ float sc[NKV_][4][SROW];               // scores / probs

  const int b = blockIdx.x, sp = blockIdx.y;
  const int tid = threadIdx.x;
  const int w = tid >> 6, l = tid & 63;             // wave = kv head g
  const int cg = l & 7, ko = l >> 3;
  const bool has_new = (sp == SPLIT_ - 1);

  // Q fragments: q4[h][i] covers cols i*32 + cg*4 .. +3 of head w*4+h
  f4 q4[4][4];
  const float* qb = qr + (size_t)(b * NH_ + w * 4) * HD_ + cg * 4;
#pragma unroll
  for (int h = 0; h < 4; ++h)
#pragma unroll
    for (int i = 0; i < 4; ++i) {
      f4 t = *(const f4*)(qb + h * HD_ + i * 32);
      q4[h][i] = t * SCALE_;
    }

  const size_t row_stride = (size_t)NKV_ * HD_;
  const float* kb = kc + ((size_t)(b * T_ + sp * KPB) * NKV_ + w) * HD_ + cg * 4;
  const float* vb = vc + ((size_t)(b * T_ + sp * KPB) * NKV_ + w) * HD_ + cg * 4;

  // ---- phase 1: scores (NIT iters x 8 keys/wave)
  {
    f4 kx[4];
    load_row4_nt(kb + (size_t)ko * row_stride, kx);
    for (int it = 0; it < NIT; ++it) {
      f4 nx[4];
      const int itn = (it + 1) & (NIT - 1);
      load_row4_nt(kb + (size_t)(itn * 8 + ko) * row_stride, nx);
      float s[4] = {0.f, 0.f, 0.f, 0.f};
#pragma unroll
      for (int i = 0; i < 4; ++i) {
#pragma unroll
        for (int h = 0; h < 4; ++h) {
          s[h] = fmaf(q4[h][i].x, kx[i].x, s[h]);
          s[h] = fmaf(q4[h][i].y, kx[i].y, s[h]);
          s[h] = fmaf(q4[h][i].z, kx[i].z, s[h]);
          s[h] = fmaf(q4[h][i].w, kx[i].w, s[h]);
        }
      }
#pragma unroll
      for (int h = 0; h < 4; ++h) {
        s[h] += __shfl_xor(s[h], 1);
        s[h] += __shfl_xor(s[h], 2);
        s[h] += __shfl_xor(s[h], 4);
      }
      if (cg == 0) {
        const int key = it * 8 + ko;
#pragma unroll
        for (int h = 0; h < 4; ++h) sc[w][h][key] = s[h];
      }
#pragma unroll
      for (int i = 0; i < 4; ++i) kx[i] = nx[i];
    }
  }

  // ---- new-token scores for the wave's 4 heads
  if (has_new) {
    const float* kp = kn + (size_t)(b * NKV_ + w) * HD_ + cg * 4;
    f4 kx2[4];
    load_row4(kp, kx2);
    float s[4] = {0.f, 0.f, 0.f, 0.f};
#pragma unroll
    for (int i = 0; i < 4; ++i) {
#pragma unroll
      for (int h = 0; h < 4; ++h) {
        s[h] = fmaf(q4[h][i].x, kx2[i].x, s[h]);
        s[h] = fmaf(q4[h][i].y, kx2[i].y, s[h]);
        s[h] = fmaf(q4[h][i].z, kx2[i].z, s[h]);
        s[h] = fmaf(q4[h][i].w, kx2[i].w, s[h]);
      }
    }
#pragma unroll
    for (int h = 0; h < 4; ++h) {
      s[h] += __shfl_xor(s[h], 1);
      s[h] += __shfl_xor(s[h], 2);
      s[h] += __shfl_xor(s[h], 4);
    }
    if (l == 0) {
#pragma unroll
      for (int h = 0; h < 4; ++h) sc[w][h][KPB] = s[h];
    }
  }

  // ---- early V issue: first V rows fly during softmax
  f4 vx[4];
  load_row4_nt(vb + (size_t)ko * row_stride, vx);

  __syncthreads();

  // ---- softmax: wave w does its 4 heads over KPB keys
#pragma unroll
  for (int h = 0; h < 4; ++h) {
    float vals[KPB / 64];
    float mloc = -1e30f;
#pragma unroll
    for (int j = 0; j < KPB / 64; ++j) {
      vals[j] = sc[w][h][j * 64 + l];
      mloc = fmaxf(mloc, vals[j]);
    }
#pragma unroll
    for (int m = 32; m > 0; m >>= 1) mloc = fmaxf(mloc, __shfl_xor(mloc, m));
    float s_extra = 0.f;
    if (has_new) {
      s_extra = sc[w][h][KPB];
      mloc = fmaxf(mloc, s_extra);
    }
    float lsum = 0.f;
#pragma unroll
    for (int j = 0; j < KPB / 64; ++j) {
      float e = expf(vals[j] - mloc);
      lsum += e;
      sc[w][h][j * 64 + l] = e;
    }
#pragma unroll
    for (int m = 32; m > 0; m >>= 1) lsum += __shfl_xor(lsum, m);
    if (has_new) {
      float en = expf(s_extra - mloc);
      lsum += en;
      if (l == 0) sc[w][h][KPB] = en;
    }
    if (l == 0) {
      float* pp = part + ((size_t)(b * NH_ + w * 4 + h) * SPLIT_ + sp) * 130;
      pp[128] = mloc;
      pp[129] = lsum;
    }
  }
  __syncthreads();

  // ---- phase 2: PV
  f4 acc[4][4];
#pragma unroll
  for (int h = 0; h < 4; ++h)
#pragma unroll
    for (int i = 0; i < 4; ++i) acc[h][i] = (f4){0.f, 0.f, 0.f, 0.f};

  for (int it = 0; it < NIT; ++it) {
    f4 nx[4];
    const int itn = (it + 1) & (NIT - 1);
    load_row4_nt(vb + (size_t)(itn * 8 + ko) * row_stride, nx);
    const int key = it * 8 + ko;
    float p[4];
#pragma unroll
    for (int h = 0; h < 4; ++h) p[h] = sc[w][h][key];
#pragma unroll
    for (int h = 0; h < 4; ++h)
#pragma unroll
      for (int i = 0; i < 4; ++i) FMA4(acc[h][i], p[h], vx[i]);
#pragma unroll
    for (int i = 0; i < 4; ++i) vx[i] = nx[i];
  }

  if (has_new && ko == 0) {   // lanes cg=0..7 cover all 128 cols once
    const float* vp = vn + (size_t)(b * NKV_ + w) * HD_ + cg * 4;
    f4 vx2[4];
    load_row4(vp, vx2);
#pragma unroll
    for (int h = 0; h < 4; ++h) {
      const float en = sc[w][h][KPB];
#pragma unroll
      for (int i = 0; i < 4; ++i) FMA4(acc[h][i], en, vx2[i]);
    }
  }

  // ---- in-wave butterfly reduce across the 8 key-owners
#pragma unroll
  for (int mask = 8; mask <= 32; mask <<= 1) {
#pragma unroll
    for (int h = 0; h < 4; ++h)
#pragma unroll
      for (int i = 0; i < 4; ++i) {
        acc[h][i].x += __shfl_xor(acc[h][i].x, mask);
        acc[h][i].y += __shfl_xor(acc[h][i].y, mask);
        acc[h][i].z += __shfl_xor(acc[h][i].z, mask);
        acc[h][i].w += __shfl_xor(acc[h][i].w, mask);
      }
  }
  if (ko == 0) {
#pragma unroll
    for (int h = 0; h < 4; ++h) {
      float* pp = part + ((size_t)(b * NH_ + w * 4 + h) * SPLIT_ + sp) * 130 + cg * 4;
#pragma unroll
      for (int i = 0; i < 4; ++i) *(f4*)(pp + i * 32) = acc[h][i];
    }
  }
}

// ---------------------------------------------------------------- merge splits
// writes ctx TRANSPOSED: ctxt[col(4096)][b(64)] so gemm2 can scalar-load it
__global__ __launch_bounds__(64) void merge_k(const float* __restrict__ part,
                                              float* __restrict__ ctxt) {
  const int bh = blockIdx.x;
  const int b = bh >> 5, h = bh & 31;
  const int l = threadIdx.x;
  const float* pbase = part + (size_t)bh * SPLIT_ * 130;
  float m_g = -1e30f;
#pragma unroll
  for (int sp = 0; sp < SPLIT_; ++sp) m_g = fmaxf(m_g, pbase[sp * 130 + 128]);
  float scale[SPLIT_];
  float l_g = 0.f;
#pragma unroll
  for (int sp = 0; sp < SPLIT_; ++sp) {
    scale[sp] = expf(pbase[sp * 130 + 128] - m_g);
    l_g += scale[sp] * pbase[sp * 130 + 129];
  }
  const float inv = 1.f / l_g;
  float c0 = 0.f, c1 = 0.f;
#pragma unroll
  for (int sp = 0; sp < SPLIT_; ++sp) {
    c0 += scale[sp] * pbase[sp * 130 + 2 * l];
    c1 += scale[sp] * pbase[sp * 130 + 2 * l + 1];
  }
  ctxt[((size_t)(h * HD_ + 2 * l)) * 64 + b] = c0 * inv;
  ctxt[((size_t)(h * HD_ + 2 * l + 1)) * 64 + b] = c1 * inv;
}

extern "C" void kernel_launch(void* const* d_in, const int* in_sizes, int n_in,
                              void* d_out, int out_size, void* d_ws, size_t ws_size,
                              hipStream_t stream) {
  const int* positions = (const int*)d_in[0];
  const float* hidden = (const float*)d_in[1];
  const float* k_cache = (const float*)d_in[2];
  const float* v_cache = (const float*)d_in[3];
  const float* w_qkv = (const float*)d_in[4];
  const float* w_o = (const float*)d_in[5];
  float* out = (float*)d_out;

  float* ws = (float*)d_ws;
  float* partA = ws;                                    // 32*64*6144 = 12582912
  float* qr = partA + (size_t)KS * 64 * QKV_COLS;       // 262144
  float* kn = qr + (size_t)64 * NH_ * HD_;              // 65536
  float* vn = kn + (size_t)64 * NKV_ * HD_;             // 65536
  float* apart = vn + (size_t)64 * NKV_ * HD_;          // 64*32*8*130 = 2129920
  float* xt = apart + (size_t)64 * NH_ * SPLIT_ * 130;  // 262144
  float* ctxt = xt + (size_t)64 * HID_;                 // 262144

  transpose_k<<<1024, 256, 0, stream>>>(hidden, xt);
  gemm_k<<<dim3(QKV_COLS / 256, 1, KS), 256, 0, stream>>>(xt, w_qkv, partA, QKV_COLS);
  reduce_rope_k<<<dim3(B_SZ, 48), 64, 0, stream>>>(partA, positions, qr, kn, vn);
  attn4_k<<<dim3(B_SZ, SPLIT_), 512, 0, stream>>>(k_cache, v_cache, qr, kn, vn, apart);
  merge_k<<<B_SZ * NH_, 64, 0, stream>>>(apart, ctxt);
  gemm_k<<<dim3(HID_ / 256, 1, KS), 256, 0, stream>>>(ctxt, w_o, partA, HID_);
  reduce_k<<<(64 * HID_) / 1024, 256, 0, stream>>>(partA, out, 64 * HID_);
}

// Round 8
// 477.400 us; speedup vs baseline: 1.5254x; 1.0361x over previous
//
#include <hip/hip_runtime.h>
#include <cstddef>

#define B_SZ 64
#define HID_ 4096
#define NH_ 32
#define NKV_ 8
#define HD_ 128
#define T_ 4096
#define QKV_COLS 6144                  // (NH + 2*NKV) * HD
#define SCALE_ 0.08838834764831845f    // 128^-0.5

#define KS 32                          // split-K for both GEMMs (768/512 blocks: keep >=2 blocks/CU!)
#define G_KCH (HID_ / KS)              // 128 k-steps per block

#define SPLIT_ 4                       // 64*4 = 256 blocks = exactly 1/CU, single round
#define KPB 1024                       // keys per (b,sp) block
#define NIT 128                        // KPB/8 keys-per-wave-iter
#define SROW 1032                      // score-row stride in LDS floats (1024 + 8 pad)

typedef float f4 __attribute__((ext_vector_type(4)));

#define FMA4(A, S, V) { A.x = fmaf(S, V.x, A.x); A.y = fmaf(S, V.y, A.y); \
                        A.z = fmaf(S, V.z, A.z); A.w = fmaf(S, V.w, A.w); }

// ---------------------------------------------------------------- X transpose
__global__ __launch_bounds__(256) void transpose_k(const float* __restrict__ X,
                                                   float* __restrict__ XT) {
  const int idx = blockIdx.x * 256 + threadIdx.x;
  const int k = idx >> 6, r = idx & 63;
  XT[idx] = X[(size_t)r * HID_ + k];
}

// ---------------------------------------------------------------- GEMM (R5 structure, plain loads)
// part[z][64][ncol] = X[64][4096] @ W[4096][ncol]; one block = 256 cols x
// ALL 64 rows x 128 k-steps. W coalesced (1 load feeds 64 FMAs); X block-
// uniform scalar loads from XT. Depth-4 named-scalar prefetch.
// 768/512 blocks -> 12/8 waves per CU (TLP is what hides latency here;
// R6 showed dropping to 1 block/CU costs 3x).
__global__ __launch_bounds__(256) void gemm_k(const float* __restrict__ XT,
                                              const float* __restrict__ W,
                                              float* __restrict__ part, int ncol) {
  const int tid = threadIdx.x;
  const int col = blockIdx.x * 256 + tid;
  const int k0 = blockIdx.z * G_KCH;

  float acc[64];
#pragma unroll
  for (int r = 0; r < 64; ++r) acc[r] = 0.f;

  const float* wp = W + (size_t)k0 * ncol + col;
  const float* xp = XT + (size_t)k0 * 64;

  float w0 = wp[0];
  float w1 = wp[(size_t)1 * ncol];
  float w2 = wp[(size_t)2 * ncol];
  float w3 = wp[(size_t)3 * ncol];

  for (int k = 0; k < G_KCH; k += 4) {
    float n0 = 0.f, n1 = 0.f, n2 = 0.f, n3 = 0.f;
    if (k + 4 < G_KCH) {
      const float* wq = wp + (size_t)(k + 4) * ncol;
      n0 = wq[0];
      n1 = wq[(size_t)1 * ncol];
      n2 = wq[(size_t)2 * ncol];
      n3 = wq[(size_t)3 * ncol];
    }
#pragma unroll
    for (int u = 0; u < 4; ++u) {
      const float wv = (u == 0) ? w0 : (u == 1) ? w1 : (u == 2) ? w2 : w3;
      const float* xk = xp + (size_t)(k + u) * 64;   // block-uniform -> s_load
#pragma unroll
      for (int r = 0; r < 64; ++r) acc[r] = fmaf(xk[r], wv, acc[r]);
    }
    w0 = n0; w1 = n1; w2 = n2; w3 = n3;
  }

  float* pp = part + (size_t)blockIdx.z * 64 * ncol + col;
#pragma unroll
  for (int r = 0; r < 64; ++r) pp[(size_t)r * ncol] = acc[r];
}

__global__ __launch_bounds__(256) void reduce_k(const float* __restrict__ part,
                                                float* __restrict__ out, int n) {
  const int i4 = (blockIdx.x * 256 + threadIdx.x) * 4;
  if (i4 >= n) return;
  float4 s = *(const float4*)(part + i4);
#pragma unroll
  for (int k = 1; k < KS; ++k) {
    float4 t = *(const float4*)(part + (size_t)k * n + i4);
    s.x += t.x; s.y += t.y; s.z += t.z; s.w += t.w;
  }
  *(float4*)(out + i4) = s;
}

// ---------------------------------------------------------------- fused reduce(KS partials) + RoPE
// grid (b, 48): hh 0..31 q heads -> qr, 32..39 k heads -> kn, 40..47 v -> vn
__global__ __launch_bounds__(64) void reduce_rope_k(const float* __restrict__ part,
                                                    const int* __restrict__ pos,
                                                    float* __restrict__ qr,
                                                    float* __restrict__ kn,
                                                    float* __restrict__ vn) {
  const int b = blockIdx.x;
  const int hh = blockIdx.y;
  const int d = threadIdx.x;            // 0..63 (pair index)
  const size_t base = (size_t)b * QKV_COLS + hh * HD_ + d;
  float s0 = 0.f, s1 = 0.f;
#pragma unroll
  for (int k = 0; k < KS; ++k) {
    const float* pk = part + (size_t)k * 64 * QKV_COLS + base;
    s0 += pk[0];
    s1 += pk[64];
  }
  if (hh < 40) {
    const float p = (float)pos[b];
    const float invf = (float)pow(10000.0, -(double)d / 64.0);
    float sn, cs;
    sincosf(p * invf, &sn, &cs);
    const float o0 = s0 * cs - s1 * sn;
    const float o1 = s1 * cs + s0 * sn;
    if (hh < 32) {
      float* dst = qr + ((size_t)b * NH_ + hh) * HD_;
      dst[d] = o0;
      dst[d + 64] = o1;
    } else {
      float* dst = kn + ((size_t)b * NKV_ + (hh - 32)) * HD_;
      dst[d] = o0;
      dst[d + 64] = o1;
    }
  } else {
    float* dst = vn + ((size_t)b * NKV_ + (hh - 40)) * HD_;
    dst[d] = s0;
    dst[d + 64] = s1;
  }
}

// ---------------------------------------------------------------- attention
__device__ __forceinline__ void load_row4_nt(const float* p, f4 r[4]) {
  r[0] = __builtin_nontemporal_load((const f4*)(p));
  r[1] = __builtin_nontemporal_load((const f4*)(p + 32));
  r[2] = __builtin_nontemporal_load((const f4*)(p + 64));
  r[3] = __builtin_nontemporal_load((const f4*)(p + 96));
}
__device__ __forceinline__ void load_row4(const float* p, f4 r[4]) {
  r[0] = *(const f4*)(p);
  r[1] = *(const f4*)(p + 32);
  r[2] = *(const f4*)(p + 64);
  r[3] = *(const f4*)(p + 96);
}

// Block = (b, split): 8 waves, wave w = kv-head g=w. The 8 waves together
// consume every byte of each 4KB key row -> sequential HBM streaming.
// 8 lanes/key (cg), 8 key-owners/wave (ko). Q + PV acc in registers;
// cross-ko reduce via shfl butterfly (no LDS).
// SPLIT_=4 -> 256 blocks = exactly 1/CU, single scheduling round.
__global__ __launch_bounds__(512, 2) void attn4_k(const float* __restrict__ kc,
                                                  const float* __restrict__ vc,
                                                  const float* __restrict__ qr,
                                                  const float* __restrict__ kn,
                                                  const float* __restrict__ vn,
                                                  float* __restrict__ part) {
  __shared__ float sc[NKV_][4][SROW];               // scores / probs (129 KB)

  const int b = blockIdx.x, sp = blockIdx.y;
  const int tid = threadIdx.x;
  const int w = tid >> 6, l = tid & 63;             // wave = kv head g
  const int cg = l & 7, ko = l >> 3;
  const bool has_new = (sp == SPLIT_ - 1);

  // Q fragments: q4[h][i] covers cols i*32 + cg*4 .. +3 of head w*4+h
  f4 q4[4][4];
  const float* qb = qr + (size_t)(b * NH_ + w * 4) * HD_ + cg * 4;
#pragma unroll
  for (int h = 0; h < 4; ++h)
#pragma unroll
    for (int i = 0; i < 4; ++i) {
      f4 t = *(const f4*)(qb + h * HD_ + i * 32);
      q4[h][i] = t * SCALE_;
    }

  const size_t row_stride = (size_t)NKV_ * HD_;
  const float* kb = kc + ((size_t)(b * T_ + sp * KPB) * NKV_ + w) * HD_ + cg * 4;
  const float* vb = vc + ((size_t)(b * T_ + sp * KPB) * NKV_ + w) * HD_ + cg * 4;

  // ---- phase 1: scores (NIT iters x 8 keys/wave)
  {
    f4 kx[4];
    load_row4_nt(kb + (size_t)ko * row_stride, kx);
    for (int it = 0; it < NIT; ++it) {
      f4 nx[4];
      const int itn = (it + 1) & (NIT - 1);
      load_row4_nt(kb + (size_t)(itn * 8 + ko) * row_stride, nx);
      float s[4] = {0.f, 0.f, 0.f, 0.f};
#pragma unroll
      for (int i = 0; i < 4; ++i) {
#pragma unroll
        for (int h = 0; h < 4; ++h) {
          s[h] = fmaf(q4[h][i].x, kx[i].x, s[h]);
          s[h] = fmaf(q4[h][i].y, kx[i].y, s[h]);
          s[h] = fmaf(q4[h][i].z, kx[i].z, s[h]);
          s[h] = fmaf(q4[h][i].w, kx[i].w, s[h]);
        }
      }
#pragma unroll
      for (int h = 0; h < 4; ++h) {
        s[h] += __shfl_xor(s[h], 1);
        s[h] += __shfl_xor(s[h], 2);
        s[h] += __shfl_xor(s[h], 4);
      }
      if (cg == 0) {
        const int key = it * 8 + ko;
#pragma unroll
        for (int h = 0; h < 4; ++h) sc[w][h][key] = s[h];
      }
#pragma unroll
      for (int i = 0; i < 4; ++i) kx[i] = nx[i];
    }
  }

  // ---- new-token scores for the wave's 4 heads
  if (has_new) {
    const float* kp = kn + (size_t)(b * NKV_ + w) * HD_ + cg * 4;
    f4 kx2[4];
    load_row4(kp, kx2);
    float s[4] = {0.f, 0.f, 0.f, 0.f};
#pragma unroll
    for (int i = 0; i < 4; ++i) {
#pragma unroll
      for (int h = 0; h < 4; ++h) {
        s[h] = fmaf(q4[h][i].x, kx2[i].x, s[h]);
        s[h] = fmaf(q4[h][i].y, kx2[i].y, s[h]);
        s[h] = fmaf(q4[h][i].z, kx2[i].z, s[h]);
        s[h] = fmaf(q4[h][i].w, kx2[i].w, s[h]);
      }
    }
#pragma unroll
    for (int h = 0; h < 4; ++h) {
      s[h] += __shfl_xor(s[h], 1);
      s[h] += __shfl_xor(s[h], 2);
      s[h] += __shfl_xor(s[h], 4);
    }
    if (l == 0) {
#pragma unroll
      for (int h = 0; h < 4; ++h) sc[w][h][KPB] = s[h];
    }
  }

  // ---- early V issue: first V rows fly during softmax
  f4 vx[4];
  load_row4_nt(vb + (size_t)ko * row_stride, vx);

  __syncthreads();

  // ---- softmax: wave w does its 4 heads over KPB keys
#pragma unroll
  for (int h = 0; h < 4; ++h) {
    float vals[KPB / 64];
    float mloc = -1e30f;
#pragma unroll
    for (int j = 0; j < KPB / 64; ++j) {
      vals[j] = sc[w][h][j * 64 + l];
      mloc = fmaxf(mloc, vals[j]);
    }
#pragma unroll
    for (int m = 32; m > 0; m >>= 1) mloc = fmaxf(mloc, __shfl_xor(mloc, m));
    float s_extra = 0.f;
    if (has_new) {
      s_extra = sc[w][h][KPB];
      mloc = fmaxf(mloc, s_extra);
    }
    float lsum = 0.f;
#pragma unroll
    for (int j = 0; j < KPB / 64; ++j) {
      float e = expf(vals[j] - mloc);
      lsum += e;
      sc[w][h][j * 64 + l] = e;
    }
#pragma unroll
    for (int m = 32; m > 0; m >>= 1) lsum += __shfl_xor(lsum, m);
    if (has_new) {
      float en = expf(s_extra - mloc);
      lsum += en;
      if (l == 0) sc[w][h][KPB] = en;
    }
    if (l == 0) {
      float* pp = part + ((size_t)(b * NH_ + w * 4 + h) * SPLIT_ + sp) * 130;
      pp[128] = mloc;
      pp[129] = lsum;
    }
  }
  __syncthreads();

  // ---- phase 2: PV
  f4 acc[4][4];
#pragma unroll
  for (int h = 0; h < 4; ++h)
#pragma unroll
    for (int i = 0; i < 4; ++i) acc[h][i] = (f4){0.f, 0.f, 0.f, 0.f};

  for (int it = 0; it < NIT; ++it) {
    f4 nx[4];
    const int itn = (it + 1) & (NIT - 1);
    load_row4_nt(vb + (size_t)(itn * 8 + ko) * row_stride, nx);
    const int key = it * 8 + ko;
    float p[4];
#pragma unroll
    for (int h = 0; h < 4; ++h) p[h] = sc[w][h][key];
#pragma unroll
    for (int h = 0; h < 4; ++h)
#pragma unroll
      for (int i = 0; i < 4; ++i) FMA4(acc[h][i], p[h], vx[i]);
#pragma unroll
    for (int i = 0; i < 4; ++i) vx[i] = nx[i];
  }

  if (has_new && ko == 0) {   // lanes cg=0..7 cover all 128 cols once
    const float* vp = vn + (size_t)(b * NKV_ + w) * HD_ + cg * 4;
    f4 vx2[4];
    load_row4(vp, vx2);
#pragma unroll
    for (int h = 0; h < 4; ++h) {
      const float en = sc[w][h][KPB];
#pragma unroll
      for (int i = 0; i < 4; ++i) FMA4(acc[h][i], en, vx2[i]);
    }
  }

  // ---- in-wave butterfly reduce across the 8 key-owners
#pragma unroll
  for (int mask = 8; mask <= 32; mask <<= 1) {
#pragma unroll
    for (int h = 0; h < 4; ++h)
#pragma unroll
      for (int i = 0; i < 4; ++i) {
        acc[h][i].x += __shfl_xor(acc[h][i].x, mask);
        acc[h][i].y += __shfl_xor(acc[h][i].y, mask);
        acc[h][i].z += __shfl_xor(acc[h][i].z, mask);
        acc[h][i].w += __shfl_xor(acc[h][i].w, mask);
      }
  }
  if (ko == 0) {
#pragma unroll
    for (int h = 0; h < 4; ++h) {
      float* pp = part + ((size_t)(b * NH_ + w * 4 + h) * SPLIT_ + sp) * 130 + cg * 4;
#pragma unroll
      for (int i = 0; i < 4; ++i) *(f4*)(pp + i * 32) = acc[h][i];
    }
  }
}

// ---------------------------------------------------------------- merge splits
// writes ctx TRANSPOSED: ctxt[col(4096)][b(64)] so gemm2 can scalar-load it
__global__ __launch_bounds__(64) void merge_k(const float* __restrict__ part,
                                              float* __restrict__ ctxt) {
  const int bh = blockIdx.x;
  const int b = bh >> 5, h = bh & 31;
  const int l = threadIdx.x;
  const float* pbase = part + (size_t)bh * SPLIT_ * 130;
  float m_g = -1e30f;
#pragma unroll
  for (int sp = 0; sp < SPLIT_; ++sp) m_g = fmaxf(m_g, pbase[sp * 130 + 128]);
  float scale[SPLIT_];
  float l_g = 0.f;
#pragma unroll
  for (int sp = 0; sp < SPLIT_; ++sp) {
    scale[sp] = expf(pbase[sp * 130 + 128] - m_g);
    l_g += scale[sp] * pbase[sp * 130 + 129];
  }
  const float inv = 1.f / l_g;
  float c0 = 0.f, c1 = 0.f;
#pragma unroll
  for (int sp = 0; sp < SPLIT_; ++sp) {
    c0 += scale[sp] * pbase[sp * 130 + 2 * l];
    c1 += scale[sp] * pbase[sp * 130 + 2 * l + 1];
  }
  ctxt[((size_t)(h * HD_ + 2 * l)) * 64 + b] = c0 * inv;
  ctxt[((size_t)(h * HD_ + 2 * l + 1)) * 64 + b] = c1 * inv;
}

extern "C" void kernel_launch(void* const* d_in, const int* in_sizes, int n_in,
                              void* d_out, int out_size, void* d_ws, size_t ws_size,
                              hipStream_t stream) {
  const int* positions = (const int*)d_in[0];
  const float* hidden = (const float*)d_in[1];
  const float* k_cache = (const float*)d_in[2];
  const float* v_cache = (const float*)d_in[3];
  const float* w_qkv = (const float*)d_in[4];
  const float* w_o = (const float*)d_in[5];
  float* out = (float*)d_out;

  float* ws = (float*)d_ws;
  float* partA = ws;                                    // 32*64*6144 = 12582912
  float* qr = partA + (size_t)KS * 64 * QKV_COLS;       // 262144
  float* kn = qr + (size_t)64 * NH_ * HD_;              // 65536
  float* vn = kn + (size_t)64 * NKV_ * HD_;             // 65536
  float* apart = vn + (size_t)64 * NKV_ * HD_;          // 64*32*4*130 = 1064960
  float* xt = apart + (size_t)64 * NH_ * SPLIT_ * 130;  // 262144
  float* ctxt = xt + (size_t)64 * HID_;                 // 262144

  transpose_k<<<1024, 256, 0, stream>>>(hidden, xt);
  gemm_k<<<dim3(QKV_COLS / 256, 1, KS), 256, 0, stream>>>(xt, w_qkv, partA, QKV_COLS);
  reduce_rope_k<<<dim3(B_SZ, 48), 64, 0, stream>>>(partA, positions, qr, kn, vn);
  attn4_k<<<dim3(B_SZ, SPLIT_), 512, 0, stream>>>(k_cache, v_cache, qr, kn, vn, apart);
  merge_k<<<B_SZ * NH_, 64, 0, stream>>>(apart, ctxt);
  gemm_k<<<dim3(HID_ / 256, 1, KS), 256, 0, stream>>>(ctxt, w_o, partA, HID_);
  reduce_k<<<(64 * HID_) / 1024, 256, 0, stream>>>(partA, out, 64 * HID_);
}